// Round 2
// baseline (2795.137 us; speedup 1.0000x reference)
//
#include <hip/hip_runtime.h>
#include <hip/hip_bf16.h>
#include <math.h>

using bf16 = __hip_bfloat16;
using short8 = __attribute__((ext_vector_type(8))) short;
using floatx4 = __attribute__((ext_vector_type(4))) float;

constexpr int B = 64;
constexpr int N = 197;
constexpr int C = 768;
constexpr int NH = 12;
constexpr int HD = 64;
constexpr int HID = 3072;
constexpr int M = B * N;          // 12608 = 197 * 64
constexpr float EPS = 1e-5f;

__device__ __forceinline__ float b2f(bf16 v) { return __bfloat162float(v); }
__device__ __forceinline__ bf16 f2b(float v) { return __float2bfloat16(v); }

// ---------------- f32 -> bf16 conversion (weights) -------------------------
__global__ void cvt_kernel(const float* __restrict__ src, bf16* __restrict__ dst, int n) {
  int i = blockIdx.x * 256 + threadIdx.x;
  if (i < n) dst[i] = f2b(src[i]);
}

// ---------------- block-wide sum over 256 threads (4 waves) ----------------
__device__ __forceinline__ float block_sum(float v, float* red) {
  #pragma unroll
  for (int off = 32; off >= 1; off >>= 1) v += __shfl_xor(v, off, 64);
  int w = threadIdx.x >> 6;
  if ((threadIdx.x & 63) == 0) red[w] = v;
  __syncthreads();
  float r = red[0] + red[1] + red[2] + red[3];
  __syncthreads();
  return r;
}

// ---------------- Kernel 1: LA pooling + channel MLP + fusion --------------
// grid: B*49 blocks, 256 threads. Writes fusion7 (B,16,7,7) f32.
__global__ void la_pool_kernel(const float* __restrict__ x,
                               const float* __restrict__ f1w, const float* __restrict__ f1bias,
                               const float* __restrict__ f2w, const float* __restrict__ f2bias,
                               const float* __restrict__ vw,  const float* __restrict__ vbias,
                               float* __restrict__ fusion7) {
  int blk = blockIdx.x;
  int b = blk / 49, p = blk % 49;
  int h7 = p / 7, w7 = p % 7;
  int tid = threadIdx.x;
  int head = tid >> 4;     // 0..15
  int j = tid & 15;        // 0..15  (16 threads cover 48 ch x 4 tokens)

  float sum = 0.f, mx = -3.0e38f;
  #pragma unroll
  for (int a = 0; a < 2; ++a) {
    #pragma unroll
    for (int bb = 0; bb < 2; ++bb) {
      int tok = 1 + (2 * h7 + a) * 14 + (2 * w7 + bb);
      const float* row = x + ((size_t)b * N + tok) * C + head * 48;
      #pragma unroll
      for (int s = 0; s < 3; ++s) {
        float v = row[j + 16 * s];
        sum += v;
        mx = fmaxf(mx, v);
      }
    }
  }
  // reduce across the 16 lanes of this head-group
  #pragma unroll
  for (int off = 8; off >= 1; off >>= 1) {
    sum += __shfl_xor(sum, off, 64);
    mx = fmaxf(mx, __shfl_xor(mx, off, 64));
  }
  __shared__ float s_mean[16], s_max[16];
  if (j == 0) { s_mean[head] = sum / 192.f; s_max[head] = mx; }
  __syncthreads();
  if (tid < 16) {
    float hm = f1bias[0], hx = hm;
    #pragma unroll
    for (int h = 0; h < 16; ++h) {
      float w = f1w[h];
      hm += s_mean[h] * w;
      hx += s_max[h] * w;
    }
    hm = fmaxf(hm, 0.f);
    hx = fmaxf(hx, 0.f);
    float w2 = f2w[tid], b2v = f2bias[tid];
    float m   = hm * w2 + b2v;
    float mxv = hx * w2 + b2v;
    float fus = vw[0] * m + vw[1] * mxv + vbias[0];
    fusion7[((size_t)b * 16 + tid) * 49 + p] = fus;
  }
}

// ---------------- Kernel 2: gate (bilinear resize + sigmoid) + LN1 ---------
__global__ void gate_ln1_kernel(const float* __restrict__ x, const float* __restrict__ fusion7,
                                const float* __restrict__ g, const float* __restrict__ beta,
                                bf16* __restrict__ ln1) {
  int blk = blockIdx.x;
  int b = blk / N, n = blk % N;
  int tid = threadIdx.x;
  __shared__ float gates[16];
  __shared__ float red[4];

  if (tid < 16) {
    if (n > 0) {
      int hh = (n - 1) / 14, ww = (n - 1) % 14;
      float ch = fminf(fmaxf(hh * 0.5f - 0.25f, 0.f), 6.f);
      float cw = fminf(fmaxf(ww * 0.5f - 0.25f, 0.f), 6.f);
      int h0 = (int)floorf(ch); int h1 = min(h0 + 1, 6); float fh = ch - (float)h0;
      int w0 = (int)floorf(cw); int w1 = min(w0 + 1, 6); float fw = cw - (float)w0;
      const float* fp = fusion7 + ((size_t)b * 16 + tid) * 49;
      float v00 = fp[h0 * 7 + w0], v01 = fp[h0 * 7 + w1];
      float v10 = fp[h1 * 7 + w0], v11 = fp[h1 * 7 + w1];
      float v = (1.f - fh) * ((1.f - fw) * v00 + fw * v01)
              + fh        * ((1.f - fw) * v10 + fw * v11);
      gates[tid] = 1.f / (1.f + expf(-v));
    } else {
      gates[tid] = 0.f;   // cls token: multiplier (1+0) == identity
    }
  }
  __syncthreads();

  const float* xr = x + ((size_t)b * N + n) * C;
  float v[3];
  #pragma unroll
  for (int s = 0; s < 3; ++s) {
    int c = tid + 256 * s;
    v[s] = xr[c] * (1.f + gates[c / 48]);
  }
  float mu = block_sum(v[0] + v[1] + v[2], red) * (1.f / 768.f);
  float d0 = v[0] - mu, d1 = v[1] - mu, d2 = v[2] - mu;
  float var = block_sum(d0 * d0 + d1 * d1 + d2 * d2, red) * (1.f / 768.f);
  float rs = rsqrtf(var + EPS);
  bf16* orow = ln1 + ((size_t)b * N + n) * C;
  #pragma unroll
  for (int s = 0; s < 3; ++s) {
    int c = tid + 256 * s;
    orow[c] = f2b((v[s] - mu) * rs * g[c] + beta[c]);
  }
}

// ---------------- Kernel 3: LN over f32 input -> bf16 ----------------------
__global__ void ln_f32_kernel(const float* __restrict__ xin,
                              const float* __restrict__ g, const float* __restrict__ beta,
                              bf16* __restrict__ out) {
  int row = blockIdx.x;
  int tid = threadIdx.x;
  __shared__ float red[4];
  const float* xr = xin + (size_t)row * C;
  float v[3];
  #pragma unroll
  for (int s = 0; s < 3; ++s) v[s] = xr[tid + 256 * s];
  float mu = block_sum(v[0] + v[1] + v[2], red) * (1.f / 768.f);
  float d0 = v[0] - mu, d1 = v[1] - mu, d2 = v[2] - mu;
  float var = block_sum(d0 * d0 + d1 * d1 + d2 * d2, red) * (1.f / 768.f);
  float rs = rsqrtf(var + EPS);
  bf16* orow = out + (size_t)row * C;
  #pragma unroll
  for (int s = 0; s < 3; ++s) {
    int c = tid + 256 * s;
    orow[c] = f2b((v[s] - mu) * rs * g[c] + beta[c]);
  }
}

// ---------------- Kernel 4: GEMM  C[M,Nc] = A[M,K] * W[Nc,K]^T + bias ------
// EPI: 0 = bias only, 1 = bias + exact gelu (before residual)
template <int EPI>
__global__ void gemm_bt(const bf16* __restrict__ A, const bf16* __restrict__ W,
                        const float* __restrict__ bias,
                        const float* __restrict__ resF,
                        bf16* __restrict__ outB, float* __restrict__ outF,
                        int Nc, int K) {
  int tid = threadIdx.x;
  int wave = tid >> 6, lane = tid & 63;
  int quad = lane >> 4, l16 = lane & 15;
  int m_base = blockIdx.x * 64 + wave * 16;
  int n_base = blockIdx.y * 64;

  const bf16* arow = A + (size_t)(m_base + l16) * K + quad * 8;
  floatx4 acc[4] = {floatx4{0,0,0,0}, floatx4{0,0,0,0}, floatx4{0,0,0,0}, floatx4{0,0,0,0}};

  for (int k0 = 0; k0 < K; k0 += 32) {
    short8 af = *reinterpret_cast<const short8*>(arow + k0);
    #pragma unroll
    for (int t = 0; t < 4; ++t) {
      const bf16* wrow = W + (size_t)(n_base + t * 16 + l16) * K + quad * 8 + k0;
      short8 bfv = *reinterpret_cast<const short8*>(wrow);
      acc[t] = __builtin_amdgcn_mfma_f32_16x16x32_bf16(af, bfv, acc[t], 0, 0, 0);
    }
  }

  int row0 = m_base + quad * 4;
  #pragma unroll
  for (int t = 0; t < 4; ++t) {
    int col = n_base + t * 16 + l16;
    float bv = bias[col];
    #pragma unroll
    for (int r = 0; r < 4; ++r) {
      int rr = row0 + r;
      float vacc = acc[t][r] + bv;
      if (EPI == 1) vacc = 0.5f * vacc * (1.f + erff(vacc * 0.7071067811865475f));
      size_t idx = (size_t)rr * Nc + col;
      if (resF) vacc += resF[idx];
      if (outF) outF[idx] = vacc;
      if (outB) outB[idx] = f2b(vacc);
    }
  }
}

// ---------------- Kernel 5: attention (per b, head, 16-row q tile) ---------
__global__ void attn_kernel(const bf16* __restrict__ qkv, bf16* __restrict__ attn_o) {
  int blk = blockIdx.x;                 // ((b*NH + h)*13 + qt)
  int qt = blk % 13;
  int bh = blk / 13;
  int h = bh % NH, b = bh / NH;
  int tid = threadIdx.x;

  __shared__ float kv[N * HD];          // 50432 B (K then V)
  __shared__ float sc[16 * 200];        // 12800 B

  const bf16* base = qkv + (size_t)b * N * 2304;

  for (int idx = tid; idx < N * HD; idx += 256) {
    int m = idx >> 6, d = idx & 63;
    kv[idx] = b2f(base[(size_t)m * 2304 + 768 + h * 64 + d]);
  }

  int qi = tid >> 4;
  int jl = tid & 15;
  int qrow = qt * 16 + qi;
  bool qvalid = (qrow < N);

  float qreg[64];
  if (qvalid) {
    const bf16* qp = base + (size_t)qrow * 2304 + h * 64;
    #pragma unroll
    for (int d = 0; d < 64; ++d) qreg[d] = b2f(qp[d]);
  }
  __syncthreads();

  if (qvalid) {
    for (int j = jl; j < N; j += 16) {
      const float4* kr = reinterpret_cast<const float4*>(&kv[j * 64]);
      float s = 0.f;
      #pragma unroll
      for (int d4 = 0; d4 < 16; ++d4) {
        float4 kk = kr[d4];
        s += qreg[4 * d4 + 0] * kk.x + qreg[4 * d4 + 1] * kk.y
           + qreg[4 * d4 + 2] * kk.z + qreg[4 * d4 + 3] * kk.w;
      }
      sc[qi * 200 + j] = s * 0.125f;
    }
  }
  float mxv = -3.0e38f;
  if (qvalid) for (int j = jl; j < N; j += 16) mxv = fmaxf(mxv, sc[qi * 200 + j]);
  #pragma unroll
  for (int off = 8; off >= 1; off >>= 1) mxv = fmaxf(mxv, __shfl_xor(mxv, off, 64));
  float sum = 0.f;
  if (qvalid) for (int j = jl; j < N; j += 16) {
    float e = expf(sc[qi * 200 + j] - mxv);
    sc[qi * 200 + j] = e;
    sum += e;
  }
  #pragma unroll
  for (int off = 8; off >= 1; off >>= 1) sum += __shfl_xor(sum, off, 64);
  float inv = 1.f / sum;

  __syncthreads();
  for (int idx = tid; idx < N * HD; idx += 256) {
    int m = idx >> 6, d = idx & 63;
    kv[idx] = b2f(base[(size_t)m * 2304 + 1536 + h * 64 + d]);
  }
  __syncthreads();

  if (qvalid) {
    int dbase = jl * 4;
    float a0 = 0.f, a1 = 0.f, a2 = 0.f, a3 = 0.f;
    for (int m = 0; m < N; ++m) {
      float p = sc[qi * 200 + m];
      const float4 vv = *reinterpret_cast<const float4*>(&kv[m * 64 + dbase]);
      a0 += p * vv.x; a1 += p * vv.y; a2 += p * vv.z; a3 += p * vv.w;
    }
    bf16* op = attn_o + ((size_t)b * N + qrow) * C + h * 64 + dbase;
    op[0] = f2b(a0 * inv); op[1] = f2b(a1 * inv);
    op[2] = f2b(a2 * inv); op[3] = f2b(a3 * inv);
  }
}

// ---------------- host-side orchestration ----------------------------------
extern "C" void kernel_launch(void* const* d_in, const int* in_sizes, int n_in,
                              void* d_out, int out_size, void* d_ws, size_t ws_size,
                              hipStream_t stream) {
  (void)in_sizes; (void)n_in; (void)out_size; (void)ws_size;
  const float* x       = (const float*)d_in[0];
  const float* norm1_g = (const float*)d_in[1];
  const float* norm1_b = (const float*)d_in[2];
  const float* qkv_w   = (const float*)d_in[3];
  const float* qkv_b   = (const float*)d_in[4];
  const float* proj_w  = (const float*)d_in[5];
  const float* proj_b  = (const float*)d_in[6];
  const float* norm2_g = (const float*)d_in[7];
  const float* norm2_b = (const float*)d_in[8];
  const float* fc1_w   = (const float*)d_in[9];
  const float* fc1_b   = (const float*)d_in[10];
  const float* fc2_w   = (const float*)d_in[11];
  const float* fc2_b   = (const float*)d_in[12];
  const float* f1_w    = (const float*)d_in[13];
  const float* f1_b    = (const float*)d_in[14];
  const float* f2_w    = (const float*)d_in[15];
  const float* f2_b    = (const float*)d_in[16];
  const float* v_w     = (const float*)d_in[17];
  const float* v_b     = (const float*)d_in[18];
  float* out = (float*)d_out;

  char* ws = (char*)d_ws;
  float* fusion7 = (float*)(ws + 0);                        //    200,704
  bf16*  qkv_wb  = (bf16*)(ws + 262144);                    //  3,538,944
  bf16*  proj_wb = (bf16*)(ws + 262144 + 3538944);          //  1,179,648
  bf16*  fc1_wb  = (bf16*)(ws + 262144 + 4718592);          //  4,718,592
  bf16*  fc2_wb  = (bf16*)(ws + 262144 + 9437184);          //  4,718,592
  bf16*  ln1     = (bf16*)(ws + 14680064);                  // 19,365,888 (reused as attn_o)
  bf16*  attn_o  = ln1;
  bf16*  qkvb    = (bf16*)(ws + 34045952);                  // 58,097,664 (region 77,463,552; reused as hbuf)
  bf16*  hbuf    = qkvb;
  float* x2      = (float*)(ws + 111509504);                // 38,731,776
  bf16*  ln2     = (bf16*)(ws + 150241280);                 // 19,365,888 (end 169,607,168)

  cvt_kernel<<<(2304 * 768 + 255) / 256, 256, 0, stream>>>(qkv_w, qkv_wb, 2304 * 768);
  cvt_kernel<<<(768 * 768 + 255) / 256, 256, 0, stream>>>(proj_w, proj_wb, 768 * 768);
  cvt_kernel<<<(HID * 768 + 255) / 256, 256, 0, stream>>>(fc1_w, fc1_wb, HID * 768);
  cvt_kernel<<<(768 * HID + 255) / 256, 256, 0, stream>>>(fc2_w, fc2_wb, 768 * HID);

  la_pool_kernel<<<B * 49, 256, 0, stream>>>(x, f1_w, f1_b, f2_w, f2_b, v_w, v_b, fusion7);
  gate_ln1_kernel<<<B * N, 256, 0, stream>>>(x, fusion7, norm1_g, norm1_b, ln1);
  gemm_bt<0><<<dim3(M / 64, 2304 / 64), 256, 0, stream>>>(
      ln1, qkv_wb, qkv_b, nullptr, qkvb, nullptr, 2304, 768);
  attn_kernel<<<B * NH * 13, 256, 0, stream>>>(qkvb, attn_o);
  gemm_bt<0><<<dim3(M / 64, 768 / 64), 256, 0, stream>>>(
      attn_o, proj_wb, proj_b, x, nullptr, x2, 768, 768);
  ln_f32_kernel<<<M, 256, 0, stream>>>(x2, norm2_g, norm2_b, ln2);
  gemm_bt<1><<<dim3(M / 64, HID / 64), 256, 0, stream>>>(
      ln2, fc1_wb, fc1_b, nullptr, hbuf, nullptr, HID, 768);
  gemm_bt<0><<<dim3(M / 64, 768 / 64), 256, 0, stream>>>(
      hbuf, fc2_wb, fc2_b, x2, nullptr, out, 768, HID);
}

// Round 3
// 1835.950 us; speedup vs baseline: 1.5224x; 1.5224x over previous
//
#include <hip/hip_runtime.h>
#include <hip/hip_bf16.h>
#include <math.h>

using bf16 = __hip_bfloat16;
using short8 = __attribute__((ext_vector_type(8))) short;
using floatx4 = __attribute__((ext_vector_type(4))) float;

constexpr int B = 64;
constexpr int N = 197;
constexpr int C = 768;
constexpr int NH = 12;
constexpr int HD = 64;
constexpr int HID = 3072;
constexpr int M = B * N;          // 12608 = 197 * 64
constexpr float EPS = 1e-5f;

__device__ __forceinline__ float b2f(bf16 v) { return __bfloat162float(v); }
__device__ __forceinline__ bf16 f2b(float v) { return __float2bfloat16(v); }

// ---------------- f32 -> bf16 conversion (weights) -------------------------
__global__ void cvt_kernel(const float* __restrict__ src, bf16* __restrict__ dst, int n) {
  int i = blockIdx.x * 256 + threadIdx.x;
  if (i < n) dst[i] = f2b(src[i]);
}

// ---------------- block-wide sum over 256 threads (4 waves) ----------------
__device__ __forceinline__ float block_sum(float v, float* red) {
  #pragma unroll
  for (int off = 32; off >= 1; off >>= 1) v += __shfl_xor(v, off, 64);
  int w = threadIdx.x >> 6;
  if ((threadIdx.x & 63) == 0) red[w] = v;
  __syncthreads();
  float r = red[0] + red[1] + red[2] + red[3];
  __syncthreads();
  return r;
}

// ---------------- Kernel 1: LA pooling + channel MLP + fusion --------------
__global__ void la_pool_kernel(const float* __restrict__ x,
                               const float* __restrict__ f1w, const float* __restrict__ f1bias,
                               const float* __restrict__ f2w, const float* __restrict__ f2bias,
                               const float* __restrict__ vw,  const float* __restrict__ vbias,
                               float* __restrict__ fusion7) {
  int blk = blockIdx.x;
  int b = blk / 49, p = blk % 49;
  int h7 = p / 7, w7 = p % 7;
  int tid = threadIdx.x;
  int head = tid >> 4;     // 0..15
  int j = tid & 15;        // 0..15

  float sum = 0.f, mx = -3.0e38f;
  #pragma unroll
  for (int a = 0; a < 2; ++a) {
    #pragma unroll
    for (int bb = 0; bb < 2; ++bb) {
      int tok = 1 + (2 * h7 + a) * 14 + (2 * w7 + bb);
      const float* row = x + ((size_t)b * N + tok) * C + head * 48;
      #pragma unroll
      for (int s = 0; s < 3; ++s) {
        float v = row[j + 16 * s];
        sum += v;
        mx = fmaxf(mx, v);
      }
    }
  }
  #pragma unroll
  for (int off = 8; off >= 1; off >>= 1) {
    sum += __shfl_xor(sum, off, 64);
    mx = fmaxf(mx, __shfl_xor(mx, off, 64));
  }
  __shared__ float s_mean[16], s_max[16];
  if (j == 0) { s_mean[head] = sum / 192.f; s_max[head] = mx; }
  __syncthreads();
  if (tid < 16) {
    float hm = f1bias[0], hx = hm;
    #pragma unroll
    for (int h = 0; h < 16; ++h) {
      float w = f1w[h];
      hm += s_mean[h] * w;
      hx += s_max[h] * w;
    }
    hm = fmaxf(hm, 0.f);
    hx = fmaxf(hx, 0.f);
    float w2 = f2w[tid], b2v = f2bias[tid];
    float m   = hm * w2 + b2v;
    float mxv = hx * w2 + b2v;
    float fus = vw[0] * m + vw[1] * mxv + vbias[0];
    fusion7[((size_t)b * 16 + tid) * 49 + p] = fus;
  }
}

// ---------------- Kernel 2: gate (bilinear resize + sigmoid) + LN1 ---------
__global__ void gate_ln1_kernel(const float* __restrict__ x, const float* __restrict__ fusion7,
                                const float* __restrict__ g, const float* __restrict__ beta,
                                bf16* __restrict__ ln1) {
  int blk = blockIdx.x;
  int b = blk / N, n = blk % N;
  int tid = threadIdx.x;
  __shared__ float gates[16];
  __shared__ float red[4];

  if (tid < 16) {
    if (n > 0) {
      int hh = (n - 1) / 14, ww = (n - 1) % 14;
      float ch = fminf(fmaxf(hh * 0.5f - 0.25f, 0.f), 6.f);
      float cw = fminf(fmaxf(ww * 0.5f - 0.25f, 0.f), 6.f);
      int h0 = (int)floorf(ch); int h1 = min(h0 + 1, 6); float fh = ch - (float)h0;
      int w0 = (int)floorf(cw); int w1 = min(w0 + 1, 6); float fw = cw - (float)w0;
      const float* fp = fusion7 + ((size_t)b * 16 + tid) * 49;
      float v00 = fp[h0 * 7 + w0], v01 = fp[h0 * 7 + w1];
      float v10 = fp[h1 * 7 + w0], v11 = fp[h1 * 7 + w1];
      float v = (1.f - fh) * ((1.f - fw) * v00 + fw * v01)
              + fh        * ((1.f - fw) * v10 + fw * v11);
      gates[tid] = 1.f / (1.f + expf(-v));
    } else {
      gates[tid] = 0.f;   // cls token: multiplier (1+0) == identity
    }
  }
  __syncthreads();

  const float* xr = x + ((size_t)b * N + n) * C;
  float v[3];
  #pragma unroll
  for (int s = 0; s < 3; ++s) {
    int c = tid + 256 * s;
    v[s] = xr[c] * (1.f + gates[c / 48]);
  }
  float mu = block_sum(v[0] + v[1] + v[2], red) * (1.f / 768.f);
  float d0 = v[0] - mu, d1 = v[1] - mu, d2 = v[2] - mu;
  float var = block_sum(d0 * d0 + d1 * d1 + d2 * d2, red) * (1.f / 768.f);
  float rs = rsqrtf(var + EPS);
  bf16* orow = ln1 + ((size_t)b * N + n) * C;
  #pragma unroll
  for (int s = 0; s < 3; ++s) {
    int c = tid + 256 * s;
    orow[c] = f2b((v[s] - mu) * rs * g[c] + beta[c]);
  }
}

// ---------------- Kernel 3: LN over f32 input -> bf16 ----------------------
__global__ void ln_f32_kernel(const float* __restrict__ xin,
                              const float* __restrict__ g, const float* __restrict__ beta,
                              bf16* __restrict__ out) {
  int row = blockIdx.x;
  int tid = threadIdx.x;
  __shared__ float red[4];
  const float* xr = xin + (size_t)row * C;
  float v[3];
  #pragma unroll
  for (int s = 0; s < 3; ++s) v[s] = xr[tid + 256 * s];
  float mu = block_sum(v[0] + v[1] + v[2], red) * (1.f / 768.f);
  float d0 = v[0] - mu, d1 = v[1] - mu, d2 = v[2] - mu;
  float var = block_sum(d0 * d0 + d1 * d1 + d2 * d2, red) * (1.f / 768.f);
  float rs = rsqrtf(var + EPS);
  bf16* orow = out + (size_t)row * C;
  #pragma unroll
  for (int s = 0; s < 3; ++s) {
    int c = tid + 256 * s;
    orow[c] = f2b((v[s] - mu) * rs * g[c] + beta[c]);
  }
}

// ---------------- Kernel 4: GEMM  C[M,Nc] = A[M,K] * W[Nc,K]^T + bias ------
template <int EPI>
__global__ void gemm_bt(const bf16* __restrict__ A, const bf16* __restrict__ W,
                        const float* __restrict__ bias,
                        const float* __restrict__ resF,
                        bf16* __restrict__ outB, float* __restrict__ outF,
                        int Nc, int K) {
  int tid = threadIdx.x;
  int wave = tid >> 6, lane = tid & 63;
  int quad = lane >> 4, l16 = lane & 15;
  int m_base = blockIdx.x * 64 + wave * 16;
  int n_base = blockIdx.y * 64;

  const bf16* arow = A + (size_t)(m_base + l16) * K + quad * 8;
  floatx4 acc[4] = {floatx4{0,0,0,0}, floatx4{0,0,0,0}, floatx4{0,0,0,0}, floatx4{0,0,0,0}};

  for (int k0 = 0; k0 < K; k0 += 32) {
    short8 af = *reinterpret_cast<const short8*>(arow + k0);
    #pragma unroll
    for (int t = 0; t < 4; ++t) {
      const bf16* wrow = W + (size_t)(n_base + t * 16 + l16) * K + quad * 8 + k0;
      short8 bfv = *reinterpret_cast<const short8*>(wrow);
      acc[t] = __builtin_amdgcn_mfma_f32_16x16x32_bf16(af, bfv, acc[t], 0, 0, 0);
    }
  }

  int row0 = m_base + quad * 4;
  #pragma unroll
  for (int t = 0; t < 4; ++t) {
    int col = n_base + t * 16 + l16;
    float bv = bias[col];
    #pragma unroll
    for (int r = 0; r < 4; ++r) {
      int rr = row0 + r;
      float vacc = acc[t][r] + bv;
      if (EPI == 1) vacc = 0.5f * vacc * (1.f + erff(vacc * 0.7071067811865475f));
      size_t idx = (size_t)rr * Nc + col;
      if (resF) vacc += resF[idx];
      if (outF) outF[idx] = vacc;
      if (outB) outB[idx] = f2b(vacc);
    }
  }
}

// ---------------- Kernel 5: MFMA attention, one block per (b, head) --------
// S tiles in registers (13 x floatx4), P via per-wave LDS, V^T staged in LDS.
// All MFMA-feeding LDS reads are b128 with row strides of 232 bf16 (116 words
// = 20 mod 32 banks) -> worst 2-way aliasing (free).
__global__ void attn_mfma_kernel(const bf16* __restrict__ qkv, bf16* __restrict__ attn_o) {
  int bh = blockIdx.x;
  int h = bh % NH, b = bh / NH;
  int tid = threadIdx.x;
  int wave = tid >> 6, lane = tid & 63, quad = lane >> 4, l16 = lane & 15;

  __shared__ __align__(16) bf16 sVt[64][232];     // V^T: [d][m], m 0..223 (>=197 zero)
  __shared__ __align__(16) bf16 sP[4][16][232];   // per-wave P: [q][m], m 0..223

  const bf16* base = qkv + (size_t)b * N * 2304 + h * 64;

  // ---- stage V transposed (coalesced global reads: d = lane dim) ----
  {
    int d = tid & 63;
    for (int m = tid >> 6; m < 224; m += 4) {
      sVt[d][m] = (m < N) ? base[(size_t)m * 2304 + 1536 + d] : f2b(0.f);
    }
  }
  __syncthreads();

  const float scale = 0.125f;   // 64^-0.5

  for (int qt = wave; qt < 13; qt += 4) {
    // Q fragments (rows clamped; rows >=197 computed but never stored)
    int qr = min(qt * 16 + l16, N - 1);
    const bf16* qp = base + (size_t)qr * 2304;
    short8 aq0 = *reinterpret_cast<const short8*>(qp + quad * 8);
    short8 aq1 = *reinterpret_cast<const short8*>(qp + 32 + quad * 8);

    // ---- scores: S[q][k] for 13 K-tiles, kept in registers ----
    floatx4 s[13];
    #pragma unroll
    for (int kt = 0; kt < 13; ++kt) {
      int kr = min(kt * 16 + l16, N - 1);
      const bf16* kp = base + (size_t)kr * 2304 + 768;
      short8 bk0 = *reinterpret_cast<const short8*>(kp + quad * 8);
      short8 bk1 = *reinterpret_cast<const short8*>(kp + 32 + quad * 8);
      floatx4 acc = floatx4{0.f, 0.f, 0.f, 0.f};
      acc = __builtin_amdgcn_mfma_f32_16x16x32_bf16(aq0, bk0, acc, 0, 0, 0);
      acc = __builtin_amdgcn_mfma_f32_16x16x32_bf16(aq1, bk1, acc, 0, 0, 0);
      s[kt] = acc;
    }

    // ---- softmax over k (mask cols >= 197); lane holds rows quad*4+r ----
    bool cv[13];
    #pragma unroll
    for (int kt = 0; kt < 13; ++kt) cv[kt] = (kt * 16 + l16) < N;

    float mx[4] = {-3.0e38f, -3.0e38f, -3.0e38f, -3.0e38f};
    #pragma unroll
    for (int kt = 0; kt < 13; ++kt) {
      #pragma unroll
      for (int r = 0; r < 4; ++r) {
        float sv = s[kt][r] * scale;
        s[kt][r] = sv;
        if (cv[kt]) mx[r] = fmaxf(mx[r], sv);
      }
    }
    #pragma unroll
    for (int off = 8; off >= 1; off >>= 1) {
      #pragma unroll
      for (int r = 0; r < 4; ++r) mx[r] = fmaxf(mx[r], __shfl_xor(mx[r], off, 64));
    }
    float sum[4] = {0.f, 0.f, 0.f, 0.f};
    #pragma unroll
    for (int kt = 0; kt < 13; ++kt) {
      #pragma unroll
      for (int r = 0; r < 4; ++r) {
        float e = cv[kt] ? expf(s[kt][r] - mx[r]) : 0.f;
        s[kt][r] = e;
        sum[r] += e;
      }
    }
    #pragma unroll
    for (int off = 8; off >= 1; off >>= 1) {
      #pragma unroll
      for (int r = 0; r < 4; ++r) sum[r] += __shfl_xor(sum[r], off, 64);
    }
    float inv[4];
    #pragma unroll
    for (int r = 0; r < 4; ++r) inv[r] = 1.f / sum[r];

    // ---- P -> LDS (C-layout -> A-layout transform), incl. zero pad ----
    #pragma unroll
    for (int kt = 0; kt < 13; ++kt) {
      #pragma unroll
      for (int r = 0; r < 4; ++r)
        sP[wave][quad * 4 + r][kt * 16 + l16] = f2b(s[kt][r]);
    }
    #pragma unroll
    for (int r = 0; r < 4; ++r)
      sP[wave][quad * 4 + r][208 + l16] = f2b(0.f);

    // ---- O = P * V via MFMA (k = m-dim, 7 chunks of 32) ----
    floatx4 o[4] = {floatx4{0,0,0,0}, floatx4{0,0,0,0}, floatx4{0,0,0,0}, floatx4{0,0,0,0}};
    #pragma unroll
    for (int c = 0; c < 7; ++c) {
      short8 ap = *reinterpret_cast<const short8*>(&sP[wave][l16][c * 32 + quad * 8]);
      #pragma unroll
      for (int t = 0; t < 4; ++t) {
        short8 bv = *reinterpret_cast<const short8*>(&sVt[t * 16 + l16][c * 32 + quad * 8]);
        o[t] = __builtin_amdgcn_mfma_f32_16x16x32_bf16(ap, bv, o[t], 0, 0, 0);
      }
    }

    // ---- store O (C-layout: row = qt*16 + quad*4 + r, col = t*16 + l16) ----
    #pragma unroll
    for (int t = 0; t < 4; ++t) {
      #pragma unroll
      for (int r = 0; r < 4; ++r) {
        int qrow = qt * 16 + quad * 4 + r;
        if (qrow < N)
          attn_o[((size_t)b * N + qrow) * C + h * 64 + t * 16 + l16] = f2b(o[t][r] * inv[r]);
      }
    }
  }
}

// ---------------- host-side orchestration ----------------------------------
extern "C" void kernel_launch(void* const* d_in, const int* in_sizes, int n_in,
                              void* d_out, int out_size, void* d_ws, size_t ws_size,
                              hipStream_t stream) {
  (void)in_sizes; (void)n_in; (void)out_size; (void)ws_size;
  const float* x       = (const float*)d_in[0];
  const float* norm1_g = (const float*)d_in[1];
  const float* norm1_b = (const float*)d_in[2];
  const float* qkv_w   = (const float*)d_in[3];
  const float* qkv_b   = (const float*)d_in[4];
  const float* proj_w  = (const float*)d_in[5];
  const float* proj_b  = (const float*)d_in[6];
  const float* norm2_g = (const float*)d_in[7];
  const float* norm2_b = (const float*)d_in[8];
  const float* fc1_w   = (const float*)d_in[9];
  const float* fc1_b   = (const float*)d_in[10];
  const float* fc2_w   = (const float*)d_in[11];
  const float* fc2_b   = (const float*)d_in[12];
  const float* f1_w    = (const float*)d_in[13];
  const float* f1_b    = (const float*)d_in[14];
  const float* f2_w    = (const float*)d_in[15];
  const float* f2_b    = (const float*)d_in[16];
  const float* v_w     = (const float*)d_in[17];
  const float* v_b     = (const float*)d_in[18];
  float* out = (float*)d_out;

  char* ws = (char*)d_ws;
  float* fusion7 = (float*)(ws + 0);                        //    200,704
  bf16*  qkv_wb  = (bf16*)(ws + 262144);                    //  3,538,944
  bf16*  proj_wb = (bf16*)(ws + 262144 + 3538944);          //  1,179,648
  bf16*  fc1_wb  = (bf16*)(ws + 262144 + 4718592);          //  4,718,592
  bf16*  fc2_wb  = (bf16*)(ws + 262144 + 9437184);          //  4,718,592
  bf16*  ln1     = (bf16*)(ws + 14680064);                  // 19,365,888 (reused as attn_o)
  bf16*  attn_o  = ln1;
  bf16*  qkvb    = (bf16*)(ws + 34045952);                  // 58,097,664 (region 77,463,552; reused as hbuf)
  bf16*  hbuf    = qkvb;
  float* x2      = (float*)(ws + 111509504);                // 38,731,776
  bf16*  ln2     = (bf16*)(ws + 150241280);                 // 19,365,888 (end 169,607,168)

  cvt_kernel<<<(2304 * 768 + 255) / 256, 256, 0, stream>>>(qkv_w, qkv_wb, 2304 * 768);
  cvt_kernel<<<(768 * 768 + 255) / 256, 256, 0, stream>>>(proj_w, proj_wb, 768 * 768);
  cvt_kernel<<<(HID * 768 + 255) / 256, 256, 0, stream>>>(fc1_w, fc1_wb, HID * 768);
  cvt_kernel<<<(768 * HID + 255) / 256, 256, 0, stream>>>(fc2_w, fc2_wb, 768 * HID);

  la_pool_kernel<<<B * 49, 256, 0, stream>>>(x, f1_w, f1_b, f2_w, f2_b, v_w, v_b, fusion7);
  gate_ln1_kernel<<<B * N, 256, 0, stream>>>(x, fusion7, norm1_g, norm1_b, ln1);
  gemm_bt<0><<<dim3(M / 64, 2304 / 64), 256, 0, stream>>>(
      ln1, qkv_wb, qkv_b, nullptr, qkvb, nullptr, 2304, 768);
  attn_mfma_kernel<<<B * NH, 256, 0, stream>>>(qkvb, attn_o);
  gemm_bt<0><<<dim3(M / 64, 768 / 64), 256, 0, stream>>>(
      attn_o, proj_wb, proj_b, x, nullptr, x2, 768, 768);
  ln_f32_kernel<<<M, 256, 0, stream>>>(x2, norm2_g, norm2_b, ln2);
  gemm_bt<1><<<dim3(M / 64, HID / 64), 256, 0, stream>>>(
      ln2, fc1_wb, fc1_b, nullptr, hbuf, nullptr, HID, 768);
  gemm_bt<0><<<dim3(M / 64, 768 / 64), 256, 0, stream>>>(
      hbuf, fc2_wb, fc2_b, x2, nullptr, out, 768, HID);
}

// Round 4
// 716.881 us; speedup vs baseline: 3.8990x; 2.5610x over previous
//
#include <hip/hip_runtime.h>
#include <hip/hip_bf16.h>
#include <math.h>

using bf16 = __hip_bfloat16;
using short8 = __attribute__((ext_vector_type(8))) short;
using floatx4 = __attribute__((ext_vector_type(4))) float;

constexpr int B = 64;
constexpr int N = 197;
constexpr int C = 768;
constexpr int NH = 12;
constexpr int HD = 64;
constexpr int HID = 3072;
constexpr int M = B * N;          // 12608 = 197 * 64
constexpr int MPAD = 12672;       // 99 * 128 (ws activation buffers padded to this)
constexpr float EPS = 1e-5f;

__device__ __forceinline__ float b2f(bf16 v) { return __bfloat162float(v); }
__device__ __forceinline__ bf16 f2b(float v) { return __float2bfloat16(v); }

// async global->LDS, 16B per lane. lds dest = wave-uniform base + lane*16.
typedef const __attribute__((address_space(1))) unsigned int* gas1_t;
typedef __attribute__((address_space(3))) unsigned int* las3_t;
__device__ __forceinline__ void load_lds16(const bf16* g, bf16* l) {
  __builtin_amdgcn_global_load_lds((gas1_t)g, (las3_t)l, 16, 0, 0);
}

// ---------------- f32 -> bf16 conversion (weights) -------------------------
__global__ void cvt_kernel(const float* __restrict__ src, bf16* __restrict__ dst, int n) {
  int i = blockIdx.x * 256 + threadIdx.x;
  if (i < n) dst[i] = f2b(src[i]);
}

// ---------------- block-wide sum over 256 threads (4 waves) ----------------
__device__ __forceinline__ float block_sum(float v, float* red) {
  #pragma unroll
  for (int off = 32; off >= 1; off >>= 1) v += __shfl_xor(v, off, 64);
  int w = threadIdx.x >> 6;
  if ((threadIdx.x & 63) == 0) red[w] = v;
  __syncthreads();
  float r = red[0] + red[1] + red[2] + red[3];
  __syncthreads();
  return r;
}

// ---------------- Kernel 1: LA pooling + channel MLP + fusion --------------
__global__ void la_pool_kernel(const float* __restrict__ x,
                               const float* __restrict__ f1w, const float* __restrict__ f1bias,
                               const float* __restrict__ f2w, const float* __restrict__ f2bias,
                               const float* __restrict__ vw,  const float* __restrict__ vbias,
                               float* __restrict__ fusion7) {
  int blk = blockIdx.x;
  int b = blk / 49, p = blk % 49;
  int h7 = p / 7, w7 = p % 7;
  int tid = threadIdx.x;
  int head = tid >> 4;     // 0..15
  int j = tid & 15;        // 0..15

  float sum = 0.f, mx = -3.0e38f;
  #pragma unroll
  for (int a = 0; a < 2; ++a) {
    #pragma unroll
    for (int bb = 0; bb < 2; ++bb) {
      int tok = 1 + (2 * h7 + a) * 14 + (2 * w7 + bb);
      const float* row = x + ((size_t)b * N + tok) * C + head * 48;
      #pragma unroll
      for (int s = 0; s < 3; ++s) {
        float v = row[j + 16 * s];
        sum += v;
        mx = fmaxf(mx, v);
      }
    }
  }
  #pragma unroll
  for (int off = 8; off >= 1; off >>= 1) {
    sum += __shfl_xor(sum, off, 64);
    mx = fmaxf(mx, __shfl_xor(mx, off, 64));
  }
  __shared__ float s_mean[16], s_max[16];
  if (j == 0) { s_mean[head] = sum / 192.f; s_max[head] = mx; }
  __syncthreads();
  if (tid < 16) {
    float hm = f1bias[0], hx = hm;
    #pragma unroll
    for (int h = 0; h < 16; ++h) {
      float w = f1w[h];
      hm += s_mean[h] * w;
      hx += s_max[h] * w;
    }
    hm = fmaxf(hm, 0.f);
    hx = fmaxf(hx, 0.f);
    float w2 = f2w[tid], b2v = f2bias[tid];
    float m   = hm * w2 + b2v;
    float mxv = hx * w2 + b2v;
    float fus = vw[0] * m + vw[1] * mxv + vbias[0];
    fusion7[((size_t)b * 16 + tid) * 49 + p] = fus;
  }
}

// ---------------- Kernel 2: gate (bilinear resize + sigmoid) + LN1 ---------
__global__ void gate_ln1_kernel(const float* __restrict__ x, const float* __restrict__ fusion7,
                                const float* __restrict__ g, const float* __restrict__ beta,
                                bf16* __restrict__ ln1) {
  int blk = blockIdx.x;
  int b = blk / N, n = blk % N;
  int tid = threadIdx.x;
  __shared__ float gates[16];
  __shared__ float red[4];

  if (tid < 16) {
    if (n > 0) {
      int hh = (n - 1) / 14, ww = (n - 1) % 14;
      float ch = fminf(fmaxf(hh * 0.5f - 0.25f, 0.f), 6.f);
      float cw = fminf(fmaxf(ww * 0.5f - 0.25f, 0.f), 6.f);
      int h0 = (int)floorf(ch); int h1 = min(h0 + 1, 6); float fh = ch - (float)h0;
      int w0 = (int)floorf(cw); int w1 = min(w0 + 1, 6); float fw = cw - (float)w0;
      const float* fp = fusion7 + ((size_t)b * 16 + tid) * 49;
      float v00 = fp[h0 * 7 + w0], v01 = fp[h0 * 7 + w1];
      float v10 = fp[h1 * 7 + w0], v11 = fp[h1 * 7 + w1];
      float v = (1.f - fh) * ((1.f - fw) * v00 + fw * v01)
              + fh        * ((1.f - fw) * v10 + fw * v11);
      gates[tid] = 1.f / (1.f + expf(-v));
    } else {
      gates[tid] = 0.f;   // cls token: multiplier (1+0) == identity
    }
  }
  __syncthreads();

  const float* xr = x + ((size_t)b * N + n) * C;
  float v[3];
  #pragma unroll
  for (int s = 0; s < 3; ++s) {
    int c = tid + 256 * s;
    v[s] = xr[c] * (1.f + gates[c / 48]);
  }
  float mu = block_sum(v[0] + v[1] + v[2], red) * (1.f / 768.f);
  float d0 = v[0] - mu, d1 = v[1] - mu, d2 = v[2] - mu;
  float var = block_sum(d0 * d0 + d1 * d1 + d2 * d2, red) * (1.f / 768.f);
  float rs = rsqrtf(var + EPS);
  bf16* orow = ln1 + ((size_t)b * N + n) * C;
  #pragma unroll
  for (int s = 0; s < 3; ++s) {
    int c = tid + 256 * s;
    orow[c] = f2b((v[s] - mu) * rs * g[c] + beta[c]);
  }
}

// ---------------- Kernel 3: LN over f32 input -> bf16 ----------------------
__global__ void ln_f32_kernel(const float* __restrict__ xin,
                              const float* __restrict__ g, const float* __restrict__ beta,
                              bf16* __restrict__ out) {
  int row = blockIdx.x;
  int tid = threadIdx.x;
  __shared__ float red[4];
  const float* xr = xin + (size_t)row * C;
  float v[3];
  #pragma unroll
  for (int s = 0; s < 3; ++s) v[s] = xr[tid + 256 * s];
  float mu = block_sum(v[0] + v[1] + v[2], red) * (1.f / 768.f);
  float d0 = v[0] - mu, d1 = v[1] - mu, d2 = v[2] - mu;
  float var = block_sum(d0 * d0 + d1 * d1 + d2 * d2, red) * (1.f / 768.f);
  float rs = rsqrtf(var + EPS);
  bf16* orow = out + (size_t)row * C;
  #pragma unroll
  for (int s = 0; s < 3; ++s) {
    int c = tid + 256 * s;
    orow[c] = f2b((v[s] - mu) * rs * g[c] + beta[c]);
  }
}

// ---------------- Kernel 4: 128x128 LDS-staged MFMA GEMM -------------------
// C[M,Nc] = A[M,K] * W[Nc,K]^T + bias.  EPI: 0 = bias, 1 = bias + exact gelu.
// A must have >= MPAD rows allocated. grid = (Nc/128, MPAD/128).
template <int EPI, int K>
__global__ void gemm128(const bf16* __restrict__ A, const bf16* __restrict__ W,
                        const float* __restrict__ bias, const float* __restrict__ resF,
                        bf16* __restrict__ outB, float* __restrict__ outF, int Nc) {
  __shared__ __align__(16) bf16 sA[128 * 32];   // row-major [128][32]
  __shared__ __align__(16) bf16 sB[128 * 32];
  int tid = threadIdx.x;
  int wave = tid >> 6, lane = tid & 63, quad = lane >> 4, l16 = lane & 15;
  int m0 = blockIdx.y * 128;
  int n0 = blockIdx.x * 128;
  int lrow = lane >> 2, kseg = lane & 3;   // staging: 16 rows x 4 segs per wave-issue

  const bf16* gA0 = A + (size_t)(m0 + wave * 16 + lrow) * K + kseg * 8;
  const bf16* gA1 = gA0 + (size_t)64 * K;
  const bf16* gB0 = W + (size_t)(n0 + wave * 16 + lrow) * K + kseg * 8;
  const bf16* gB1 = gB0 + (size_t)64 * K;
  bf16* lA0 = &sA[(wave * 16) * 32];
  bf16* lA1 = &sA[(64 + wave * 16) * 32];
  bf16* lB0 = &sB[(wave * 16) * 32];
  bf16* lB1 = &sB[(64 + wave * 16) * 32];

  int wm = (wave & 1) * 64, wn = (wave >> 1) * 64;   // wave quadrant
  floatx4 acc[4][4] = {};

  for (int k0 = 0; k0 < K; k0 += 32) {
    load_lds16(gA0 + k0, lA0);
    load_lds16(gA1 + k0, lA1);
    load_lds16(gB0 + k0, lB0);
    load_lds16(gB1 + k0, lB1);
    __syncthreads();
    short8 af[4], bw[4];
    #pragma unroll
    for (int s = 0; s < 4; ++s)
      af[s] = *reinterpret_cast<const short8*>(&sA[(wm + s * 16 + l16) * 32 + quad * 8]);
    #pragma unroll
    for (int t = 0; t < 4; ++t)
      bw[t] = *reinterpret_cast<const short8*>(&sB[(wn + t * 16 + l16) * 32 + quad * 8]);
    #pragma unroll
    for (int s = 0; s < 4; ++s)
      #pragma unroll
      for (int t = 0; t < 4; ++t)
        acc[s][t] = __builtin_amdgcn_mfma_f32_16x16x32_bf16(af[s], bw[t], acc[s][t], 0, 0, 0);
    __syncthreads();
  }

  #pragma unroll
  for (int t = 0; t < 4; ++t) {
    int col = n0 + wn + t * 16 + l16;
    float bv = bias[col];
    #pragma unroll
    for (int s = 0; s < 4; ++s) {
      int rowb = m0 + wm + s * 16 + quad * 4;
      #pragma unroll
      for (int r = 0; r < 4; ++r) {
        int row = rowb + r;
        if (row < M) {
          float v = acc[s][t][r] + bv;
          if (EPI == 1) v = 0.5f * v * (1.f + erff(v * 0.7071067811865475f));
          size_t idx = (size_t)row * Nc + col;
          if (resF) v += resF[idx];
          if (outF) outF[idx] = v;
          if (outB) outB[idx] = f2b(v);
        }
      }
    }
  }
}

// ---------------- Kernel 5: MFMA attention, one block per (b, head) --------
__global__ void attn_mfma_kernel(const bf16* __restrict__ qkv, bf16* __restrict__ attn_o) {
  int bh = blockIdx.x;
  int h = bh % NH, b = bh / NH;
  int tid = threadIdx.x;
  int wave = tid >> 6, lane = tid & 63, quad = lane >> 4, l16 = lane & 15;

  __shared__ __align__(16) bf16 sVt[64][232];     // V^T: [d][m], m 0..223 (>=197 zero)
  __shared__ __align__(16) bf16 sP[4][16][232];   // per-wave P: [q][m]

  const bf16* base = qkv + (size_t)b * N * 2304 + h * 64;

  {
    int d = tid & 63;
    for (int m = tid >> 6; m < 224; m += 4) {
      sVt[d][m] = (m < N) ? base[(size_t)m * 2304 + 1536 + d] : f2b(0.f);
    }
  }
  __syncthreads();

  const float scale = 0.125f;   // 64^-0.5

  for (int qt = wave; qt < 13; qt += 4) {
    int qr = min(qt * 16 + l16, N - 1);
    const bf16* qp = base + (size_t)qr * 2304;
    short8 aq0 = *reinterpret_cast<const short8*>(qp + quad * 8);
    short8 aq1 = *reinterpret_cast<const short8*>(qp + 32 + quad * 8);

    floatx4 s[13];
    #pragma unroll
    for (int kt = 0; kt < 13; ++kt) {
      int kr = min(kt * 16 + l16, N - 1);
      const bf16* kp = base + (size_t)kr * 2304 + 768;
      short8 bk0 = *reinterpret_cast<const short8*>(kp + quad * 8);
      short8 bk1 = *reinterpret_cast<const short8*>(kp + 32 + quad * 8);
      floatx4 acc = floatx4{0.f, 0.f, 0.f, 0.f};
      acc = __builtin_amdgcn_mfma_f32_16x16x32_bf16(aq0, bk0, acc, 0, 0, 0);
      acc = __builtin_amdgcn_mfma_f32_16x16x32_bf16(aq1, bk1, acc, 0, 0, 0);
      s[kt] = acc;
    }

    bool cv[13];
    #pragma unroll
    for (int kt = 0; kt < 13; ++kt) cv[kt] = (kt * 16 + l16) < N;

    float mx[4] = {-3.0e38f, -3.0e38f, -3.0e38f, -3.0e38f};
    #pragma unroll
    for (int kt = 0; kt < 13; ++kt) {
      #pragma unroll
      for (int r = 0; r < 4; ++r) {
        float sv = s[kt][r] * scale;
        s[kt][r] = sv;
        if (cv[kt]) mx[r] = fmaxf(mx[r], sv);
      }
    }
    #pragma unroll
    for (int off = 8; off >= 1; off >>= 1) {
      #pragma unroll
      for (int r = 0; r < 4; ++r) mx[r] = fmaxf(mx[r], __shfl_xor(mx[r], off, 64));
    }
    float sum[4] = {0.f, 0.f, 0.f, 0.f};
    #pragma unroll
    for (int kt = 0; kt < 13; ++kt) {
      #pragma unroll
      for (int r = 0; r < 4; ++r) {
        float e = cv[kt] ? expf(s[kt][r] - mx[r]) : 0.f;
        s[kt][r] = e;
        sum[r] += e;
      }
    }
    #pragma unroll
    for (int off = 8; off >= 1; off >>= 1) {
      #pragma unroll
      for (int r = 0; r < 4; ++r) sum[r] += __shfl_xor(sum[r], off, 64);
    }
    float inv[4];
    #pragma unroll
    for (int r = 0; r < 4; ++r) inv[r] = 1.f / sum[r];

    #pragma unroll
    for (int kt = 0; kt < 13; ++kt) {
      #pragma unroll
      for (int r = 0; r < 4; ++r)
        sP[wave][quad * 4 + r][kt * 16 + l16] = f2b(s[kt][r]);
    }
    #pragma unroll
    for (int r = 0; r < 4; ++r)
      sP[wave][quad * 4 + r][208 + l16] = f2b(0.f);

    floatx4 o[4] = {floatx4{0,0,0,0}, floatx4{0,0,0,0}, floatx4{0,0,0,0}, floatx4{0,0,0,0}};
    #pragma unroll
    for (int c = 0; c < 7; ++c) {
      short8 ap = *reinterpret_cast<const short8*>(&sP[wave][l16][c * 32 + quad * 8]);
      #pragma unroll
      for (int t = 0; t < 4; ++t) {
        short8 bv = *reinterpret_cast<const short8*>(&sVt[t * 16 + l16][c * 32 + quad * 8]);
        o[t] = __builtin_amdgcn_mfma_f32_16x16x32_bf16(ap, bv, o[t], 0, 0, 0);
      }
    }

    #pragma unroll
    for (int t = 0; t < 4; ++t) {
      #pragma unroll
      for (int r = 0; r < 4; ++r) {
        int qrow = qt * 16 + quad * 4 + r;
        if (qrow < N)
          attn_o[((size_t)b * N + qrow) * C + h * 64 + t * 16 + l16] = f2b(o[t][r] * inv[r]);
      }
    }
  }
}

// ---------------- host-side orchestration ----------------------------------
extern "C" void kernel_launch(void* const* d_in, const int* in_sizes, int n_in,
                              void* d_out, int out_size, void* d_ws, size_t ws_size,
                              hipStream_t stream) {
  (void)in_sizes; (void)n_in; (void)out_size; (void)ws_size;
  const float* x       = (const float*)d_in[0];
  const float* norm1_g = (const float*)d_in[1];
  const float* norm1_b = (const float*)d_in[2];
  const float* qkv_w   = (const float*)d_in[3];
  const float* qkv_b   = (const float*)d_in[4];
  const float* proj_w  = (const float*)d_in[5];
  const float* proj_b  = (const float*)d_in[6];
  const float* norm2_g = (const float*)d_in[7];
  const float* norm2_b = (const float*)d_in[8];
  const float* fc1_w   = (const float*)d_in[9];
  const float* fc1_b   = (const float*)d_in[10];
  const float* fc2_w   = (const float*)d_in[11];
  const float* fc2_b   = (const float*)d_in[12];
  const float* f1_w    = (const float*)d_in[13];
  const float* f1_b    = (const float*)d_in[14];
  const float* f2_w    = (const float*)d_in[15];
  const float* f2_b    = (const float*)d_in[16];
  const float* v_w     = (const float*)d_in[17];
  const float* v_b     = (const float*)d_in[18];
  float* out = (float*)d_out;

  char* ws = (char*)d_ws;
  // ws layout (~150.5 MB). Activation buffers padded to MPAD=12672 rows.
  float* fusion7 = (float*)(ws + 0);                //    200,704
  bf16*  qkv_wb  = (bf16*)(ws + 262144);            //  3,538,944
  bf16*  proj_wb = (bf16*)(ws + 3801088);           //  1,179,648
  bf16*  fc1_wb  = (bf16*)(ws + 4980736);           //  4,718,592
  bf16*  fc2_wb  = (bf16*)(ws + 9699328);           //  4,718,592
  bf16*  ln1     = (bf16*)(ws + 14417920);          // 19,464,192 (MPAD x 768 bf16; reused: attn_o, ln2)
  bf16*  attn_o  = ln1;
  bf16*  ln2     = ln1;                             // ln1/attn_o dead before LN2 writes
  bf16*  qkvb    = (bf16*)(ws + 33882112);          // 77,856,768 region (qkv: MPAD x 2304; reused: hbuf MPAD x 3072)
  bf16*  hbuf    = qkvb;
  float* x2      = (float*)(ws + 111738880);        // 38,731,776 (M x 768 f32) -> end 150,470,656

  cvt_kernel<<<(2304 * 768 + 255) / 256, 256, 0, stream>>>(qkv_w, qkv_wb, 2304 * 768);
  cvt_kernel<<<(768 * 768 + 255) / 256, 256, 0, stream>>>(proj_w, proj_wb, 768 * 768);
  cvt_kernel<<<(HID * 768 + 255) / 256, 256, 0, stream>>>(fc1_w, fc1_wb, HID * 768);
  cvt_kernel<<<(768 * HID + 255) / 256, 256, 0, stream>>>(fc2_w, fc2_wb, 768 * HID);

  la_pool_kernel<<<B * 49, 256, 0, stream>>>(x, f1_w, f1_b, f2_w, f2_b, v_w, v_b, fusion7);
  gate_ln1_kernel<<<B * N, 256, 0, stream>>>(x, fusion7, norm1_g, norm1_b, ln1);
  // qkv: (M x 768) x (2304 x 768)^T -> bf16
  gemm128<0, 768><<<dim3(2304 / 128, MPAD / 128), 256, 0, stream>>>(
      ln1, qkv_wb, qkv_b, nullptr, qkvb, nullptr, 2304);
  attn_mfma_kernel<<<B * NH, 256, 0, stream>>>(qkvb, attn_o);
  // proj + residual(x) -> x2 (f32)
  gemm128<0, 768><<<dim3(768 / 128, MPAD / 128), 256, 0, stream>>>(
      attn_o, proj_wb, proj_b, x, nullptr, x2, 768);
  ln_f32_kernel<<<M, 256, 0, stream>>>(x2, norm2_g, norm2_b, ln2);
  // fc1 + gelu -> hbuf (bf16)
  gemm128<1, 768><<<dim3(HID / 128, MPAD / 128), 256, 0, stream>>>(
      ln2, fc1_wb, fc1_b, nullptr, hbuf, nullptr, HID);
  // fc2 + residual(x2) -> out (f32)
  gemm128<0, 3072><<<dim3(768 / 128, MPAD / 128), 256, 0, stream>>>(
      hbuf, fc2_wb, fc2_b, x2, nullptr, out, 768);
}